// Round 9
// baseline (361.269 us; speedup 1.0000x reference)
//
#include <hip/hip_runtime.h>

typedef __attribute__((ext_vector_type(8))) __bf16 bf16x8;
typedef __attribute__((ext_vector_type(8))) short short8;
typedef __attribute__((ext_vector_type(4))) float f32x4;
typedef __attribute__((ext_vector_type(2))) unsigned int uint32x2;

__device__ __forceinline__ unsigned short f2bf(float f) {
    union { float f; unsigned int i; } c; c.f = f;
    unsigned int r = c.i + 0x7fffu + ((c.i >> 16) & 1u);  // round-nearest-even
    return (unsigned short)(r >> 16);
}

// pack two f32 -> two bf16 in one VALU op (no builtin on gfx950; m240/m214)
__device__ __forceinline__ unsigned int cvt_pk_bf16(float lo, float hi) {
    unsigned int r;
    asm("v_cvt_pk_bf16_f32 %0, %1, %2" : "=v"(r) : "v"(lo), "v"(hi));
    return r;
}

__device__ __forceinline__ bf16x8 pack_bf16x8(unsigned int a, unsigned int b,
                                              unsigned int c, unsigned int d) {
    union { unsigned int u[4]; bf16x8 v; } x;
    x.u[0] = a; x.u[1] = b; x.u[2] = c; x.u[3] = d;
    return x.v;
}

#if __has_builtin(__builtin_amdgcn_exp2f)
#define FAST_EXP2(x) __builtin_amdgcn_exp2f(x)     // single v_exp_f32
#else
#define FAST_EXP2(x) __expf((x) * 0.6931471805599453f)
#endif

// async global->LDS, 16B per lane; LDS dest must be base + lane*16 in wave order
__device__ __forceinline__ void async_cp16(const unsigned short* g, unsigned short* l) {
    __builtin_amdgcn_global_load_lds(
        (const __attribute__((address_space(1))) unsigned int*)g,
        (__attribute__((address_space(3))) unsigned int*)l, 16, 0, 0);
}

#define DIM 1024
#define NSEQ 4096
#define NH 16
#define HD 64

// T2 XOR swizzle for attn LDS: linear 64-u16 (128B) rows; XOR the 16B-slot
// index (u16 bits 3-5) with row&7. (v4/v5: conflicts 2.94e7 -> 8.4e6)
#define SWZ(row, col) (((row) << 6) + ((col) ^ (((row) & 7) << 3)))

// ---------------------------------------------------------------------------
// fp32 -> bf16 copy-convert, 8 elems/thread
// ---------------------------------------------------------------------------
__global__ __launch_bounds__(256)
void conv_kernel(const float* __restrict__ in, unsigned short* __restrict__ out)
{
    const int i = blockIdx.x * 256 + threadIdx.x;
    const float4 a0 = ((const float4*)in)[i * 2];
    const float4 a1 = ((const float4*)in)[i * 2 + 1];
    short8 v;
    v[0] = (short)f2bf(a0.x); v[1] = (short)f2bf(a0.y);
    v[2] = (short)f2bf(a0.z); v[3] = (short)f2bf(a0.w);
    v[4] = (short)f2bf(a1.x); v[5] = (short)f2bf(a1.y);
    v[6] = (short)f2bf(a1.z); v[7] = (short)f2bf(a1.w);
    ((short8*)out)[i] = v;
}

// ---------------------------------------------------------------------------
// w [K][N] fp32 -> wT [N][K] bf16, 64x64 LDS tile transpose
// ---------------------------------------------------------------------------
template<int N, int K>
__global__ __launch_bounds__(256)
void transpose_conv_kernel(const float* __restrict__ in, unsigned short* __restrict__ out)
{
    __shared__ unsigned short Ls[64][65];
    const int t  = threadIdx.x;
    const int k0 = blockIdx.x * 64, n0 = blockIdx.y * 64;
    const int kl = t >> 2, nl = (t & 3) * 16;
    const float* src = in + (size_t)(k0 + kl) * N + n0 + nl;
    #pragma unroll
    for (int i = 0; i < 4; i++) {
        float4 a = *(const float4*)(src + i * 4);
        Ls[kl][nl + i*4 + 0] = f2bf(a.x); Ls[kl][nl + i*4 + 1] = f2bf(a.y);
        Ls[kl][nl + i*4 + 2] = f2bf(a.z); Ls[kl][nl + i*4 + 3] = f2bf(a.w);
    }
    __syncthreads();
    const int kl2 = (t & 7) * 8;
    #pragma unroll
    for (int i = 0; i < 2; i++) {
        const int nl2 = (t >> 3) + i * 32;
        short8 v;
        #pragma unroll
        for (int j = 0; j < 8; j++) v[j] = (short)Ls[kl2 + j][nl2];
        *(short8*)(out + (size_t)(n0 + nl2) * K + k0 + kl2) = v;
    }
}

// ---------------------------------------------------------------------------
// m97-style GEMM: C[M x N] = A[M][1024]bf16 * Bt[N][1024]bf16^T + bias(fp32)
// 128x128 tile, BK=32, 4 waves x 64x64 quadrant, global_load_lds staging.
// MODE 0 (N=3072): scatter bf16 -> Q[Z,H,N,64], K[Z,H,N,64], V^T[Z,H,64,N]
// MODE 1 (N=1024): fp32 store to outf.
// ---------------------------------------------------------------------------
template<int MODE>
__global__ __launch_bounds__(256)
void gemm_kernel(const unsigned short* __restrict__ A,
                 const unsigned short* __restrict__ Bt,
                 const float* __restrict__ bias,
                 unsigned short* __restrict__ out0,
                 unsigned short* __restrict__ out1,
                 unsigned short* __restrict__ out2,
                 float* __restrict__ outf)
{
    __shared__ __align__(16) unsigned short As[128][32];
    __shared__ __align__(16) unsigned short Bs[128][32];
    const int t    = threadIdx.x;
    const int m0   = blockIdx.x * 128, n0 = blockIdx.y * 128;
    const int lane = t & 63, wv = t >> 6;
    const int l15  = lane & 15, quad = lane >> 4;
    const int wm   = (wv >> 1) * 64, wn = (wv & 1) * 64;
    const int sr   = wv * 16 + (lane >> 2);     // staging row (0..63)
    const int sc   = (lane & 3) * 8;            // staging col (k)
    const unsigned short* Ag = A  + (size_t)m0 * 1024;
    const unsigned short* Bg = Bt + (size_t)n0 * 1024;

    f32x4 acc[4][4] = {};

    for (int kt = 0; kt < 1024; kt += 32) {
        __syncthreads();                        // prior iter's LDS reads done
        async_cp16(Ag + (size_t)(sr)      * 1024 + kt + sc, &As[sr][sc]);
        async_cp16(Ag + (size_t)(sr + 64) * 1024 + kt + sc, &As[sr + 64][sc]);
        async_cp16(Bg + (size_t)(sr)      * 1024 + kt + sc, &Bs[sr][sc]);
        async_cp16(Bg + (size_t)(sr + 64) * 1024 + kt + sc, &Bs[sr + 64][sc]);
        __syncthreads();                        // drains vmcnt (loads landed)

        bf16x8 af[4], bfr[4];
        #pragma unroll
        for (int mi = 0; mi < 4; mi++) af[mi]  = *(const bf16x8*)&As[wm + mi*16 + l15][quad*8];
        #pragma unroll
        for (int ni = 0; ni < 4; ni++) bfr[ni] = *(const bf16x8*)&Bs[wn + ni*16 + l15][quad*8];
        #pragma unroll
        for (int mi = 0; mi < 4; mi++)
            #pragma unroll
            for (int ni = 0; ni < 4; ni++)
                acc[mi][ni] = __builtin_amdgcn_mfma_f32_16x16x32_bf16(af[mi], bfr[ni], acc[mi][ni], 0, 0, 0);
    }

    #pragma unroll
    for (int mi = 0; mi < 4; mi++) {
        #pragma unroll
        for (int ni = 0; ni < 4; ni++) {
            const int col  = n0 + wn + ni*16 + l15;
            const float bval = bias[col];
            #pragma unroll
            for (int r = 0; r < 4; r++) {
                const int row = m0 + wm + mi*16 + quad*4 + r;
                const float val = acc[mi][ni][r] + bval;
                if (MODE == 0) {
                    const int which = col >> 10;          // 0=q 1=k 2=v
                    const int rem   = col & 1023;
                    const int h = rem >> 6, dd = rem & 63;
                    const int bb = row >> 12, ns = row & 4095;
                    if (which == 2) {
                        out2[((size_t)((bb * NH + h) * HD + dd)) * NSEQ + ns] = f2bf(val);
                    } else {
                        const size_t off = ((size_t)((bb * NH + h) * NSEQ + ns)) * HD + dd;
                        ((which == 0) ? out0 : out1)[off] = f2bf(val);
                    }
                } else {
                    outf[(size_t)row * 1024 + col] = val;
                }
            }
        }
    }
}

// ---------------------------------------------------------------------------
// Flash attention: block=(z,h,128 q-rows), 4 waves x 32 rows.
// v10 = v6 + l-sum via ones-MFMA: l[q] = sum_k P[q][k] = (P . 1^T), computed
// by 2 extra MFMAs per mi with B = all-ones bf16x8 (kappa-permutation of A is
// irrelevant against constant B). Moves ~64 cy/tile of v_add work from the
// saturated VALU pipe (60%) to the 34%-busy MFMA pipe, AND delivers l in the
// C layout (row = quad*4+r) so the epilogue shuffle redistribution is gone;
// divisor now sums the bf16-rounded P actually used in PV.
// Everything else identical to v6/v9 (proven 361 us / attn 178.5 us).
// ---------------------------------------------------------------------------
#define C_LOG2E 0.1803368801111183f    // 0.125 * log2(e)
#define M_LOG2  11.541560327111707f    // 8 * log2(e)

__global__ __launch_bounds__(256, 4)
void attn_kernel(const unsigned short* __restrict__ qb,
                 const unsigned short* __restrict__ kb,
                 const unsigned short* __restrict__ vb,
                 unsigned short* __restrict__ ob)
{
    __shared__ __align__(16) unsigned short Ks[2][64 * 64];
    __shared__ __align__(16) unsigned short Vt[2][64 * 64];

    const int t    = threadIdx.x;
    const int wv   = t >> 6, lane = t & 63, l15 = lane & 15, quad = lane >> 4;
    const int q0   = blockIdx.x * 128;
    const int h    = blockIdx.y, b = blockIdx.z;
    const size_t bh = (size_t)(b * NH + h) * NSEQ * HD;
    const unsigned short* Qp  = qb + bh;
    const unsigned short* Kp  = kb + bh;
    const unsigned short* Vtp = vb + bh;

    bf16x8 aq[2][2];
    #pragma unroll
    for (int mi = 0; mi < 2; mi++) {
        const unsigned short* qrow =
            Qp + (size_t)(q0 + wv*32 + mi*16 + l15) * HD + quad*8;
        aq[mi][0] = *(const bf16x8*)(qrow);
        aq[mi][1] = *(const bf16x8*)(qrow + 32);
    }

    const bf16x8 ones8 = pack_bf16x8(0x3F803F80u, 0x3F803F80u,
                                     0x3F803F80u, 0x3F803F80u);  // 8x bf16 1.0

    f32x4 acc_l[2] = {};           // l[q] per C-layout row (quad*4+r)
    f32x4 acc_o[2][4] = {};

    const int srow = lane >> 3;                        // 0..7
    const int sg8  = ((lane & 7) ^ srow) * 8;          // u16 src granule off
    const int rA   = wv * 16 + srow;                   // rows, call 0
    const int rB   = rA + 8;                           // rows, call 1
    unsigned short* ldsKA0 = &Ks[0][(wv*16 + 0) * 64];
    unsigned short* ldsKB0 = &Ks[0][(wv*16 + 8) * 64];
    unsigned short* ldsVA0 = &Vt[0][(wv*16 + 0) * 64];
    unsigned short* ldsVB0 = &Vt[0][(wv*16 + 8) * 64];
    unsigned short* ldsKA1 = &Ks[1][(wv*16 + 0) * 64];
    unsigned short* ldsKB1 = &Ks[1][(wv*16 + 8) * 64];
    unsigned short* ldsVA1 = &Vt[1][(wv*16 + 0) * 64];
    unsigned short* ldsVB1 = &Vt[1][(wv*16 + 8) * 64];

    // prologue: stage tile 0 into buffer 0
    async_cp16(Kp  + (size_t)rA * HD + sg8,   ldsKA0);
    async_cp16(Kp  + (size_t)rB * HD + sg8,   ldsKB0);
    async_cp16(Vtp + (size_t)rA * NSEQ + sg8, ldsVA0);
    async_cp16(Vtp + (size_t)rB * NSEQ + sg8, ldsVB0);

    int cur = 0;
    for (int kt = 0; kt < NSEQ; kt += 64) {
        __syncthreads();   // drains vmcnt (buf[cur] staged) + block barrier

        // issue next tile into buf[cur^1]; flies under this tile's compute.
        if (kt + 64 < NSEQ) {
            const int ktn = kt + 64;
            async_cp16(Kp  + (size_t)(ktn + rA) * HD + sg8, cur ? ldsKA0 : ldsKA1);
            async_cp16(Kp  + (size_t)(ktn + rB) * HD + sg8, cur ? ldsKB0 : ldsKB1);
            async_cp16(Vtp + (size_t)rA * NSEQ + ktn + sg8, cur ? ldsVA0 : ldsVA1);
            async_cp16(Vtp + (size_t)rB * NSEQ + ktn + sg8, cur ? ldsVB0 : ldsVB1);
        }

        const unsigned short* Kc = Ks[cur];
        const unsigned short* Vc = Vt[cur];

        // S^T = K Q^T (swapped operands): lane owns
        // S[q = l15][k = nj*16 + quad*4 + r], r = 0..3 contiguous.
        f32x4 accs[2][4] = {};
        __builtin_amdgcn_s_setprio(1);
        #pragma unroll
        for (int nj = 0; nj < 4; nj++) {
            bf16x8 bk0 = *(const bf16x8*)&Kc[SWZ(nj*16 + l15, quad*8)];
            bf16x8 bk1 = *(const bf16x8*)&Kc[SWZ(nj*16 + l15, 32 + quad*8)];
            #pragma unroll
            for (int mi = 0; mi < 2; mi++) {
                accs[mi][nj] = __builtin_amdgcn_mfma_f32_16x16x32_bf16(bk0, aq[mi][0], accs[mi][nj], 0, 0, 0);
                accs[mi][nj] = __builtin_amdgcn_mfma_f32_16x16x32_bf16(bk1, aq[mi][1], accs[mi][nj], 0, 0, 0);
            }
        }
        __builtin_amdgcn_s_setprio(0);

        // fixed-max softmax: p = 2^(s*c - M); P stays in registers.
        uint2 pw[2][4];
        #pragma unroll
        for (int mi = 0; mi < 2; mi++) {
            #pragma unroll
            for (int nj = 0; nj < 4; nj++) {
                const float p0 = FAST_EXP2(fmaf(accs[mi][nj][0], C_LOG2E, -M_LOG2));
                const float p1 = FAST_EXP2(fmaf(accs[mi][nj][1], C_LOG2E, -M_LOG2));
                const float p2 = FAST_EXP2(fmaf(accs[mi][nj][2], C_LOG2E, -M_LOG2));
                const float p3 = FAST_EXP2(fmaf(accs[mi][nj][3], C_LOG2E, -M_LOG2));
                pw[mi][nj].x = cvt_pk_bf16(p0, p1);
                pw[mi][nj].y = cvt_pk_bf16(p2, p3);
            }
        }

        // P A-fragments (kappa order), shared by l-MFMA and PV
        bf16x8 apf[2][2];
        #pragma unroll
        for (int mi = 0; mi < 2; mi++)
            #pragma unroll
            for (int W = 0; W < 2; W++)
                apf[mi][W] = pack_bf16x8(pw[mi][2*W].x,   pw[mi][2*W].y,
                                         pw[mi][2*W+1].x, pw[mi][2*W+1].y);

        __builtin_amdgcn_s_setprio(1);
        // l[q] += P . 1^T : D[i][j] = sum_k P[i][k] (same for all j); lands
        // in C layout row = quad*4+r — exactly acc_o's row mapping.
        #pragma unroll
        for (int mi = 0; mi < 2; mi++) {
            acc_l[mi] = __builtin_amdgcn_mfma_f32_16x16x32_bf16(apf[mi][0], ones8, acc_l[mi], 0, 0, 0);
            acc_l[mi] = __builtin_amdgcn_mfma_f32_16x16x32_bf16(apf[mi][1], ones8, acc_l[mi], 0, 0, 0);
        }

        // O += P V with kappa-permuted fragments (k = 32W+16(j>>2)+4q+(j&3))
        #pragma unroll
        for (int njd = 0; njd < 4; njd++) {
            const int drow = njd * 16 + l15;
            #pragma unroll
            for (int W = 0; W < 2; W++) {
                const uint32x2 lo = *(const uint32x2*)&Vc[SWZ(drow, W*32 + quad*4)];
                const uint32x2 hi = *(const uint32x2*)&Vc[SWZ(drow, W*32 + 16 + quad*4)];
                const bf16x8 bv = pack_bf16x8(lo[0], lo[1], hi[0], hi[1]);
                #pragma unroll
                for (int mi = 0; mi < 2; mi++) {
                    acc_o[mi][njd] = __builtin_amdgcn_mfma_f32_16x16x32_bf16(apf[mi][W], bv, acc_o[mi][njd], 0, 0, 0);
                }
            }
        }
        __builtin_amdgcn_s_setprio(0);

        cur ^= 1;
    }

    // acc_l[mi][r] = l for row quad*4+r — no cross-lane redistribution needed.
    #pragma unroll
    for (int mi = 0; mi < 2; mi++) {
        #pragma unroll
        for (int r = 0; r < 4; r++) {
            const float inv = 1.0f / acc_l[mi][r];
            const int row = q0 + wv*32 + mi*16 + quad*4 + r;
            const size_t base = ((size_t)(b * NSEQ + row)) * DIM + h * HD;
            #pragma unroll
            for (int nj = 0; nj < 4; nj++)
                ob[base + nj*16 + l15] = f2bf(acc_o[mi][nj][r] * inv);
        }
    }
}

extern "C" void kernel_launch(void* const* d_in, const int* in_sizes, int n_in,
                              void* d_out, int out_size, void* d_ws, size_t ws_size,
                              hipStream_t stream)
{
    const float *x = nullptr, *w_qkv = nullptr, *b_qkv = nullptr,
                *w_o = nullptr, *b_o = nullptr;
    for (int i = 0; i < n_in; i++) {
        switch (in_sizes[i]) {
            case 8388608: x     = (const float*)d_in[i]; break;
            case 3145728: w_qkv = (const float*)d_in[i]; break;
            case 3072:    b_qkv = (const float*)d_in[i]; break;
            case 1048576: w_o   = (const float*)d_in[i]; break;
            case 1024:    b_o   = (const float*)d_in[i]; break;
        }
    }
    float* out = (float*)d_out;                     // [2,4096,1024] fp32

    const size_t WQB  = (size_t)3072 * 1024;        // elems
    const size_t WOB  = (size_t)1024 * 1024;
    const size_t SEGB = (size_t)NSEQ * DIM;         // 4,194,304 elems / batch

    char* p = (char*)d_ws;
    unsigned short* wqb = (unsigned short*)p;  p += WQB * 2;
    unsigned short* wob = (unsigned short*)p;  p += WOB * 2;

    transpose_conv_kernel<3072, 1024><<<dim3(16, 48), 256, 0, stream>>>(w_qkv, wqb);
    transpose_conv_kernel<1024, 1024><<<dim3(16, 16), 256, 0, stream>>>(w_o, wob);

    const size_t tier1_bytes = (WQB + WOB + 2*SEGB + 3*2*SEGB) * 2;  // 75.5 MB
    if (ws_size >= tier1_bytes) {
        unsigned short* xb = (unsigned short*)p;  p += 2 * SEGB * 2;
        unsigned short* qb = (unsigned short*)p;  p += 2 * SEGB * 2;
        unsigned short* kb = (unsigned short*)p;  p += 2 * SEGB * 2;
        unsigned short* vb = (unsigned short*)p;
        unsigned short* ao = xb;                  // xb dead after GEMM1
        conv_kernel<<<4096, 256, 0, stream>>>(x, xb);
        gemm_kernel<0><<<dim3(64, 24), 256, 0, stream>>>(xb, wqb, b_qkv, qb, kb, vb, nullptr);
        attn_kernel<<<dim3(32, NH, 2), 256, 0, stream>>>(qb, kb, vb, ao);
        gemm_kernel<1><<<dim3(64, 8), 256, 0, stream>>>(ao, wob, b_o, nullptr, nullptr, nullptr, out);
    } else {
        // per-batch: peak 41.9 MB
        unsigned short* xb = (unsigned short*)p;  p += SEGB * 2;
        unsigned short* qb = (unsigned short*)p;  p += SEGB * 2;
        unsigned short* kb = (unsigned short*)p;  p += SEGB * 2;
        unsigned short* vb = (unsigned short*)p;
        unsigned short* ao = xb;
        for (int b = 0; b < 2; b++) {
            conv_kernel<<<2048, 256, 0, stream>>>(x + b * SEGB, xb);
            gemm_kernel<0><<<dim3(32, 24), 256, 0, stream>>>(xb, wqb, b_qkv, qb, kb, vb, nullptr);
            attn_kernel<<<dim3(32, NH, 1), 256, 0, stream>>>(qb, kb, vb, ao);
            gemm_kernel<1><<<dim3(32, 8), 256, 0, stream>>>(ao, wob, b_o, nullptr, nullptr, nullptr, out + b * SEGB);
        }
    }
}

// Round 10
// 345.049 us; speedup vs baseline: 1.0470x; 1.0470x over previous
//
#include <hip/hip_runtime.h>

typedef __attribute__((ext_vector_type(8))) __bf16 bf16x8;
typedef __attribute__((ext_vector_type(8))) short short8;
typedef __attribute__((ext_vector_type(4))) float f32x4;
typedef __attribute__((ext_vector_type(2))) unsigned int uint32x2;

#define C_LOG2E 0.1803368801111183f    // 0.125 * log2(e)  (softmax scale, exp2 domain)
#define M_LOG2  11.541560327111707f    // 8 * log2(e)      (fixed-max shift)

__device__ __forceinline__ unsigned short f2bf(float f) {
    union { float f; unsigned int i; } c; c.f = f;
    unsigned int r = c.i + 0x7fffu + ((c.i >> 16) & 1u);  // round-nearest-even
    return (unsigned short)(r >> 16);
}

// pack two f32 -> two bf16 in one VALU op (no builtin on gfx950; m240/m214)
__device__ __forceinline__ unsigned int cvt_pk_bf16(float lo, float hi) {
    unsigned int r;
    asm("v_cvt_pk_bf16_f32 %0, %1, %2" : "=v"(r) : "v"(lo), "v"(hi));
    return r;
}

__device__ __forceinline__ bf16x8 pack_bf16x8(unsigned int a, unsigned int b,
                                              unsigned int c, unsigned int d) {
    union { unsigned int u[4]; bf16x8 v; } x;
    x.u[0] = a; x.u[1] = b; x.u[2] = c; x.u[3] = d;
    return x.v;
}

#if __has_builtin(__builtin_amdgcn_exp2f)
#define FAST_EXP2(x) __builtin_amdgcn_exp2f(x)     // single v_exp_f32
#else
#define FAST_EXP2(x) __expf((x) * 0.6931471805599453f)
#endif

// async global->LDS, 16B per lane; LDS dest must be base + lane*16 in wave order
__device__ __forceinline__ void async_cp16(const unsigned short* g, unsigned short* l) {
    __builtin_amdgcn_global_load_lds(
        (const __attribute__((address_space(1))) unsigned int*)g,
        (__attribute__((address_space(3))) unsigned int*)l, 16, 0, 0);
}

#define DIM 1024
#define NSEQ 4096
#define NH 16
#define HD 64

// T2 XOR swizzle for attn LDS: linear 64-u16 (128B) rows; XOR the 16B-slot
// index (u16 bits 3-5) with row&7. (v4/v5: conflicts 2.94e7 -> 8.4e6)
#define SWZ(row, col) (((row) << 6) + ((col) ^ (((row) & 7) << 3)))

// ---------------------------------------------------------------------------
// fp32 -> bf16 copy-convert, 8 elems/thread
// ---------------------------------------------------------------------------
__global__ __launch_bounds__(256)
void conv_kernel(const float* __restrict__ in, unsigned short* __restrict__ out)
{
    const int i = blockIdx.x * 256 + threadIdx.x;
    const float4 a0 = ((const float4*)in)[i * 2];
    const float4 a1 = ((const float4*)in)[i * 2 + 1];
    short8 v;
    v[0] = (short)f2bf(a0.x); v[1] = (short)f2bf(a0.y);
    v[2] = (short)f2bf(a0.z); v[3] = (short)f2bf(a0.w);
    v[4] = (short)f2bf(a1.x); v[5] = (short)f2bf(a1.y);
    v[6] = (short)f2bf(a1.z); v[7] = (short)f2bf(a1.w);
    ((short8*)out)[i] = v;
}

// ---------------------------------------------------------------------------
// w [K][N] fp32 -> wT [N][K] bf16, 64x64 LDS tile transpose
// ---------------------------------------------------------------------------
template<int N, int K>
__global__ __launch_bounds__(256)
void transpose_conv_kernel(const float* __restrict__ in, unsigned short* __restrict__ out)
{
    __shared__ unsigned short Ls[64][65];
    const int t  = threadIdx.x;
    const int k0 = blockIdx.x * 64, n0 = blockIdx.y * 64;
    const int kl = t >> 2, nl = (t & 3) * 16;
    const float* src = in + (size_t)(k0 + kl) * N + n0 + nl;
    #pragma unroll
    for (int i = 0; i < 4; i++) {
        float4 a = *(const float4*)(src + i * 4);
        Ls[kl][nl + i*4 + 0] = f2bf(a.x); Ls[kl][nl + i*4 + 1] = f2bf(a.y);
        Ls[kl][nl + i*4 + 2] = f2bf(a.z); Ls[kl][nl + i*4 + 3] = f2bf(a.w);
    }
    __syncthreads();
    const int kl2 = (t & 7) * 8;
    #pragma unroll
    for (int i = 0; i < 2; i++) {
        const int nl2 = (t >> 3) + i * 32;
        short8 v;
        #pragma unroll
        for (int j = 0; j < 8; j++) v[j] = (short)Ls[kl2 + j][nl2];
        *(short8*)(out + (size_t)(n0 + nl2) * K + k0 + kl2) = v;
    }
}

// ---------------------------------------------------------------------------
// m97-style GEMM: C[M x N] = A[M][1024]bf16 * Bt[N][1024]bf16^T + bias(fp32)
// 128x128 tile, BK=32, 4 waves x 64x64 quadrant, global_load_lds staging.
// MODE 0 (N=3072): scatter bf16 -> Q[Z,H,N,64], K[Z,H,N,64], V^T[Z,H,64,N].
//   v11: Q (which==0) is stored PRE-SCALED by C_LOG2E so attn's softmax can
//   drop its per-score fma (same single bf16 rounding, exact fold).
// MODE 1 (N=1024): fp32 store to outf.
// ---------------------------------------------------------------------------
template<int MODE>
__global__ __launch_bounds__(256)
void gemm_kernel(const unsigned short* __restrict__ A,
                 const unsigned short* __restrict__ Bt,
                 const float* __restrict__ bias,
                 unsigned short* __restrict__ out0,
                 unsigned short* __restrict__ out1,
                 unsigned short* __restrict__ out2,
                 float* __restrict__ outf)
{
    __shared__ __align__(16) unsigned short As[128][32];
    __shared__ __align__(16) unsigned short Bs[128][32];
    const int t    = threadIdx.x;
    const int m0   = blockIdx.x * 128, n0 = blockIdx.y * 128;
    const int lane = t & 63, wv = t >> 6;
    const int l15  = lane & 15, quad = lane >> 4;
    const int wm   = (wv >> 1) * 64, wn = (wv & 1) * 64;
    const int sr   = wv * 16 + (lane >> 2);     // staging row (0..63)
    const int sc   = (lane & 3) * 8;            // staging col (k)
    const unsigned short* Ag = A  + (size_t)m0 * 1024;
    const unsigned short* Bg = Bt + (size_t)n0 * 1024;

    f32x4 acc[4][4] = {};

    for (int kt = 0; kt < 1024; kt += 32) {
        __syncthreads();                        // prior iter's LDS reads done
        async_cp16(Ag + (size_t)(sr)      * 1024 + kt + sc, &As[sr][sc]);
        async_cp16(Ag + (size_t)(sr + 64) * 1024 + kt + sc, &As[sr + 64][sc]);
        async_cp16(Bg + (size_t)(sr)      * 1024 + kt + sc, &Bs[sr][sc]);
        async_cp16(Bg + (size_t)(sr + 64) * 1024 + kt + sc, &Bs[sr + 64][sc]);
        __syncthreads();                        // drains vmcnt (loads landed)

        bf16x8 af[4], bfr[4];
        #pragma unroll
        for (int mi = 0; mi < 4; mi++) af[mi]  = *(const bf16x8*)&As[wm + mi*16 + l15][quad*8];
        #pragma unroll
        for (int ni = 0; ni < 4; ni++) bfr[ni] = *(const bf16x8*)&Bs[wn + ni*16 + l15][quad*8];
        #pragma unroll
        for (int mi = 0; mi < 4; mi++)
            #pragma unroll
            for (int ni = 0; ni < 4; ni++)
                acc[mi][ni] = __builtin_amdgcn_mfma_f32_16x16x32_bf16(af[mi], bfr[ni], acc[mi][ni], 0, 0, 0);
    }

    #pragma unroll
    for (int mi = 0; mi < 4; mi++) {
        #pragma unroll
        for (int ni = 0; ni < 4; ni++) {
            const int col  = n0 + wn + ni*16 + l15;
            const float bval = bias[col];
            #pragma unroll
            for (int r = 0; r < 4; r++) {
                const int row = m0 + wm + mi*16 + quad*4 + r;
                const float val = acc[mi][ni][r] + bval;
                if (MODE == 0) {
                    const int which = col >> 10;          // 0=q 1=k 2=v
                    const int rem   = col & 1023;
                    const int h = rem >> 6, dd = rem & 63;
                    const int bb = row >> 12, ns = row & 4095;
                    if (which == 2) {
                        out2[((size_t)((bb * NH + h) * HD + dd)) * NSEQ + ns] = f2bf(val);
                    } else {
                        const size_t off = ((size_t)((bb * NH + h) * NSEQ + ns)) * HD + dd;
                        if (which == 0) out0[off] = f2bf(val * C_LOG2E);  // pre-scaled Q
                        else            out1[off] = f2bf(val);
                    }
                } else {
                    outf[(size_t)row * 1024 + col] = val;
                }
            }
        }
    }
}

// ---------------------------------------------------------------------------
// Flash attention: block=(z,h,128 q-rows), 4 waves x 32 rows.
// v11 = v10 + softmax fma elimination: Q arrives pre-scaled by C_LOG2E
// (GEMM0 epilogue), and the QK accumulators are INITIALIZED to -M_LOG2
// (MFMA C-in carries the constant), so p = exp2(accs[r]) directly —
// 32 v_fma/lane/tile removed from the saturated VALU pipe.
// l-sum via ones-MFMA (v10); in-register P via kappa-permuted PV (v6);
// double-buffered global_load_lds staging; one barrier/tile.
// ---------------------------------------------------------------------------
__global__ __launch_bounds__(256, 4)
void attn_kernel(const unsigned short* __restrict__ qb,
                 const unsigned short* __restrict__ kb,
                 const unsigned short* __restrict__ vb,
                 unsigned short* __restrict__ ob)
{
    __shared__ __align__(16) unsigned short Ks[2][64 * 64];
    __shared__ __align__(16) unsigned short Vt[2][64 * 64];

    const int t    = threadIdx.x;
    const int wv   = t >> 6, lane = t & 63, l15 = lane & 15, quad = lane >> 4;
    const int q0   = blockIdx.x * 128;
    const int h    = blockIdx.y, b = blockIdx.z;
    const size_t bh = (size_t)(b * NH + h) * NSEQ * HD;
    const unsigned short* Qp  = qb + bh;
    const unsigned short* Kp  = kb + bh;
    const unsigned short* Vtp = vb + bh;

    bf16x8 aq[2][2];
    #pragma unroll
    for (int mi = 0; mi < 2; mi++) {
        const unsigned short* qrow =
            Qp + (size_t)(q0 + wv*32 + mi*16 + l15) * HD + quad*8;
        aq[mi][0] = *(const bf16x8*)(qrow);
        aq[mi][1] = *(const bf16x8*)(qrow + 32);
    }

    const bf16x8 ones8 = pack_bf16x8(0x3F803F80u, 0x3F803F80u,
                                     0x3F803F80u, 0x3F803F80u);  // 8x bf16 1.0
    const f32x4 minit = {-M_LOG2, -M_LOG2, -M_LOG2, -M_LOG2};

    f32x4 acc_l[2] = {};           // l[q] per C-layout row (quad*4+r)
    f32x4 acc_o[2][4] = {};

    const int srow = lane >> 3;                        // 0..7
    const int sg8  = ((lane & 7) ^ srow) * 8;          // u16 src granule off
    const int rA   = wv * 16 + srow;                   // rows, call 0
    const int rB   = rA + 8;                           // rows, call 1
    unsigned short* ldsKA0 = &Ks[0][(wv*16 + 0) * 64];
    unsigned short* ldsKB0 = &Ks[0][(wv*16 + 8) * 64];
    unsigned short* ldsVA0 = &Vt[0][(wv*16 + 0) * 64];
    unsigned short* ldsVB0 = &Vt[0][(wv*16 + 8) * 64];
    unsigned short* ldsKA1 = &Ks[1][(wv*16 + 0) * 64];
    unsigned short* ldsKB1 = &Ks[1][(wv*16 + 8) * 64];
    unsigned short* ldsVA1 = &Vt[1][(wv*16 + 0) * 64];
    unsigned short* ldsVB1 = &Vt[1][(wv*16 + 8) * 64];

    // prologue: stage tile 0 into buffer 0
    async_cp16(Kp  + (size_t)rA * HD + sg8,   ldsKA0);
    async_cp16(Kp  + (size_t)rB * HD + sg8,   ldsKB0);
    async_cp16(Vtp + (size_t)rA * NSEQ + sg8, ldsVA0);
    async_cp16(Vtp + (size_t)rB * NSEQ + sg8, ldsVB0);

    int cur = 0;
    for (int kt = 0; kt < NSEQ; kt += 64) {
        __syncthreads();   // drains vmcnt (buf[cur] staged) + block barrier

        // issue next tile into buf[cur^1]; flies under this tile's compute.
        if (kt + 64 < NSEQ) {
            const int ktn = kt + 64;
            async_cp16(Kp  + (size_t)(ktn + rA) * HD + sg8, cur ? ldsKA0 : ldsKA1);
            async_cp16(Kp  + (size_t)(ktn + rB) * HD + sg8, cur ? ldsKB0 : ldsKB1);
            async_cp16(Vtp + (size_t)rA * NSEQ + ktn + sg8, cur ? ldsVA0 : ldsVA1);
            async_cp16(Vtp + (size_t)rB * NSEQ + ktn + sg8, cur ? ldsVB0 : ldsVB1);
        }

        const unsigned short* Kc = Ks[cur];
        const unsigned short* Vc = Vt[cur];

        // S^T = K Q^T (swapped operands): lane owns
        // S[q = l15][k = nj*16 + quad*4 + r]. Accumulators start at -M_LOG2:
        // final accs = c*s - M (Q pre-scaled by c in GEMM0).
        f32x4 accs[2][4];
        #pragma unroll
        for (int mi = 0; mi < 2; mi++)
            #pragma unroll
            for (int nj = 0; nj < 4; nj++)
                accs[mi][nj] = minit;
        __builtin_amdgcn_s_setprio(1);
        #pragma unroll
        for (int nj = 0; nj < 4; nj++) {
            bf16x8 bk0 = *(const bf16x8*)&Kc[SWZ(nj*16 + l15, quad*8)];
            bf16x8 bk1 = *(const bf16x8*)&Kc[SWZ(nj*16 + l15, 32 + quad*8)];
            #pragma unroll
            for (int mi = 0; mi < 2; mi++) {
                accs[mi][nj] = __builtin_amdgcn_mfma_f32_16x16x32_bf16(bk0, aq[mi][0], accs[mi][nj], 0, 0, 0);
                accs[mi][nj] = __builtin_amdgcn_mfma_f32_16x16x32_bf16(bk1, aq[mi][1], accs[mi][nj], 0, 0, 0);
            }
        }
        __builtin_amdgcn_s_setprio(0);

        // fixed-max softmax: p = 2^(accs) — no fma needed. P stays in regs.
        uint2 pw[2][4];
        #pragma unroll
        for (int mi = 0; mi < 2; mi++) {
            #pragma unroll
            for (int nj = 0; nj < 4; nj++) {
                const float p0 = FAST_EXP2(accs[mi][nj][0]);
                const float p1 = FAST_EXP2(accs[mi][nj][1]);
                const float p2 = FAST_EXP2(accs[mi][nj][2]);
                const float p3 = FAST_EXP2(accs[mi][nj][3]);
                pw[mi][nj].x = cvt_pk_bf16(p0, p1);
                pw[mi][nj].y = cvt_pk_bf16(p2, p3);
            }
        }

        // P A-fragments (kappa order), shared by l-MFMA and PV
        bf16x8 apf[2][2];
        #pragma unroll
        for (int mi = 0; mi < 2; mi++)
            #pragma unroll
            for (int W = 0; W < 2; W++)
                apf[mi][W] = pack_bf16x8(pw[mi][2*W].x,   pw[mi][2*W].y,
                                         pw[mi][2*W+1].x, pw[mi][2*W+1].y);

        __builtin_amdgcn_s_setprio(1);
        // l[q] += P . 1^T : lands in C layout row = quad*4+r (acc_o's rows).
        #pragma unroll
        for (int mi = 0; mi < 2; mi++) {
            acc_l[mi] = __builtin_amdgcn_mfma_f32_16x16x32_bf16(apf[mi][0], ones8, acc_l[mi], 0, 0, 0);
            acc_l[mi] = __builtin_amdgcn_mfma_f32_16x16x32_bf16(apf[mi][1], ones8, acc_l[mi], 0, 0, 0);
        }

        // O += P V with kappa-permuted fragments (k = 32W+16(j>>2)+4q+(j&3))
        #pragma unroll
        for (int njd = 0; njd < 4; njd++) {
            const int drow = njd * 16 + l15;
            #pragma unroll
            for (int W = 0; W < 2; W++) {
                const uint32x2 lo = *(const uint32x2*)&Vc[SWZ(drow, W*32 + quad*4)];
                const uint32x2 hi = *(const uint32x2*)&Vc[SWZ(drow, W*32 + 16 + quad*4)];
                const bf16x8 bv = pack_bf16x8(lo[0], lo[1], hi[0], hi[1]);
                #pragma unroll
                for (int mi = 0; mi < 2; mi++) {
                    acc_o[mi][njd] = __builtin_amdgcn_mfma_f32_16x16x32_bf16(apf[mi][W], bv, acc_o[mi][njd], 0, 0, 0);
                }
            }
        }
        __builtin_amdgcn_s_setprio(0);

        cur ^= 1;
    }

    // acc_l[mi][r] = l for row quad*4+r — no cross-lane redistribution needed.
    #pragma unroll
    for (int mi = 0; mi < 2; mi++) {
        #pragma unroll
        for (int r = 0; r < 4; r++) {
            const float inv = 1.0f / acc_l[mi][r];
            const int row = q0 + wv*32 + mi*16 + quad*4 + r;
            const size_t base = ((size_t)(b * NSEQ + row)) * DIM + h * HD;
            #pragma unroll
            for (int nj = 0; nj < 4; nj++)
                ob[base + nj*16 + l15] = f2bf(acc_o[mi][nj][r] * inv);
        }
    }
}

extern "C" void kernel_launch(void* const* d_in, const int* in_sizes, int n_in,
                              void* d_out, int out_size, void* d_ws, size_t ws_size,
                              hipStream_t stream)
{
    const float *x = nullptr, *w_qkv = nullptr, *b_qkv = nullptr,
                *w_o = nullptr, *b_o = nullptr;
    for (int i = 0; i < n_in; i++) {
        switch (in_sizes[i]) {
            case 8388608: x     = (const float*)d_in[i]; break;
            case 3145728: w_qkv = (const float*)d_in[i]; break;
            case 3072:    b_qkv = (const float*)d_in[i]; break;
            case 1048576: w_o   = (const float*)d_in[i]; break;
            case 1024:    b_o   = (const float*)d_in[i]; break;
        }
    }
    float* out = (float*)d_out;                     // [2,4096,1024] fp32

    const size_t WQB  = (size_t)3072 * 1024;        // elems
    const size_t WOB  = (size_t)1024 * 1024;
    const size_t SEGB = (size_t)NSEQ * DIM;         // 4,194,304 elems / batch

    char* p = (char*)d_ws;
    unsigned short* wqb = (unsigned short*)p;  p += WQB * 2;
    unsigned short* wob = (unsigned short*)p;  p += WOB * 2;

    transpose_conv_kernel<3072, 1024><<<dim3(16, 48), 256, 0, stream>>>(w_qkv, wqb);
    transpose_conv_kernel<1024, 1024><<<dim3(16, 16), 256, 0, stream>>>(w_o, wob);

    const size_t tier1_bytes = (WQB + WOB + 2*SEGB + 3*2*SEGB) * 2;  // 75.5 MB
    if (ws_size >= tier1_bytes) {
        unsigned short* xb = (unsigned short*)p;  p += 2 * SEGB * 2;
        unsigned short* qb = (unsigned short*)p;  p += 2 * SEGB * 2;
        unsigned short* kb = (unsigned short*)p;  p += 2 * SEGB * 2;
        unsigned short* vb = (unsigned short*)p;
        unsigned short* ao = xb;                  // xb dead after GEMM1
        conv_kernel<<<4096, 256, 0, stream>>>(x, xb);
        gemm_kernel<0><<<dim3(64, 24), 256, 0, stream>>>(xb, wqb, b_qkv, qb, kb, vb, nullptr);
        attn_kernel<<<dim3(32, NH, 2), 256, 0, stream>>>(qb, kb, vb, ao);
        gemm_kernel<1><<<dim3(64, 8), 256, 0, stream>>>(ao, wob, b_o, nullptr, nullptr, nullptr, out);
    } else {
        // per-batch: peak 41.9 MB
        unsigned short* xb = (unsigned short*)p;  p += SEGB * 2;
        unsigned short* qb = (unsigned short*)p;  p += SEGB * 2;
        unsigned short* kb = (unsigned short*)p;  p += SEGB * 2;
        unsigned short* vb = (unsigned short*)p;
        unsigned short* ao = xb;
        for (int b = 0; b < 2; b++) {
            conv_kernel<<<2048, 256, 0, stream>>>(x + b * SEGB, xb);
            gemm_kernel<0><<<dim3(32, 24), 256, 0, stream>>>(xb, wqb, b_qkv, qb, kb, vb, nullptr);
            attn_kernel<<<dim3(32, NH, 1), 256, 0, stream>>>(qb, kb, vb, ao);
            gemm_kernel<1><<<dim3(32, 8), 256, 0, stream>>>(ao, wob, b_o, nullptr, nullptr, nullptr, out + b * SEGB);
        }
    }
}

// Round 11
// 341.652 us; speedup vs baseline: 1.0574x; 1.0099x over previous
//
#include <hip/hip_runtime.h>

typedef __attribute__((ext_vector_type(8))) __bf16 bf16x8;
typedef __attribute__((ext_vector_type(8))) short short8;
typedef __attribute__((ext_vector_type(4))) float f32x4;
typedef __attribute__((ext_vector_type(2))) unsigned int uint32x2;

#define C_LOG2E 0.1803368801111183f    // 0.125 * log2(e)  (softmax scale, exp2 domain)
#define M_LOG2  11.541560327111707f    // 8 * log2(e)      (fixed-max shift)

__device__ __forceinline__ unsigned short f2bf(float f) {
    union { float f; unsigned int i; } c; c.f = f;
    unsigned int r = c.i + 0x7fffu + ((c.i >> 16) & 1u);  // round-nearest-even
    return (unsigned short)(r >> 16);
}

// pack two f32 -> two bf16 in one VALU op (no builtin on gfx950; m240/m214)
__device__ __forceinline__ unsigned int cvt_pk_bf16(float lo, float hi) {
    unsigned int r;
    asm("v_cvt_pk_bf16_f32 %0, %1, %2" : "=v"(r) : "v"(lo), "v"(hi));
    return r;
}

__device__ __forceinline__ bf16x8 pack_bf16x8(unsigned int a, unsigned int b,
                                              unsigned int c, unsigned int d) {
    union { unsigned int u[4]; bf16x8 v; } x;
    x.u[0] = a; x.u[1] = b; x.u[2] = c; x.u[3] = d;
    return x.v;
}

#if __has_builtin(__builtin_amdgcn_exp2f)
#define FAST_EXP2(x) __builtin_amdgcn_exp2f(x)     // single v_exp_f32
#else
#define FAST_EXP2(x) __expf((x) * 0.6931471805599453f)
#endif

// async global->LDS, 16B per lane; LDS dest must be base + lane*16 in wave order
__device__ __forceinline__ void async_cp16(const unsigned short* g, unsigned short* l) {
    __builtin_amdgcn_global_load_lds(
        (const __attribute__((address_space(1))) unsigned int*)g,
        (__attribute__((address_space(3))) unsigned int*)l, 16, 0, 0);
}

#define DIM 1024
#define NSEQ 4096
#define NH 16
#define HD 64

// T2 XOR swizzle for attn LDS: linear 64-u16 (128B) rows; XOR the 16B-slot
// index (u16 bits 3-5) with row&7. (v4/v5: conflicts 2.94e7 -> 8.4e6)
#define SWZ(row, col) (((row) << 6) + ((col) ^ (((row) & 7) << 3)))

// ---------------------------------------------------------------------------
// fp32 -> bf16 copy-convert, 8 elems/thread
// ---------------------------------------------------------------------------
__global__ __launch_bounds__(256)
void conv_kernel(const float* __restrict__ in, unsigned short* __restrict__ out)
{
    const int i = blockIdx.x * 256 + threadIdx.x;
    const float4 a0 = ((const float4*)in)[i * 2];
    const float4 a1 = ((const float4*)in)[i * 2 + 1];
    short8 v;
    v[0] = (short)f2bf(a0.x); v[1] = (short)f2bf(a0.y);
    v[2] = (short)f2bf(a0.z); v[3] = (short)f2bf(a0.w);
    v[4] = (short)f2bf(a1.x); v[5] = (short)f2bf(a1.y);
    v[6] = (short)f2bf(a1.z); v[7] = (short)f2bf(a1.w);
    ((short8*)out)[i] = v;
}

// ---------------------------------------------------------------------------
// w [K][N] fp32 -> wT [N][K] bf16, 64x64 LDS tile transpose
// ---------------------------------------------------------------------------
template<int N, int K>
__global__ __launch_bounds__(256)
void transpose_conv_kernel(const float* __restrict__ in, unsigned short* __restrict__ out)
{
    __shared__ unsigned short Ls[64][65];
    const int t  = threadIdx.x;
    const int k0 = blockIdx.x * 64, n0 = blockIdx.y * 64;
    const int kl = t >> 2, nl = (t & 3) * 16;
    const float* src = in + (size_t)(k0 + kl) * N + n0 + nl;
    #pragma unroll
    for (int i = 0; i < 4; i++) {
        float4 a = *(const float4*)(src + i * 4);
        Ls[kl][nl + i*4 + 0] = f2bf(a.x); Ls[kl][nl + i*4 + 1] = f2bf(a.y);
        Ls[kl][nl + i*4 + 2] = f2bf(a.z); Ls[kl][nl + i*4 + 3] = f2bf(a.w);
    }
    __syncthreads();
    const int kl2 = (t & 7) * 8;
    #pragma unroll
    for (int i = 0; i < 2; i++) {
        const int nl2 = (t >> 3) + i * 32;
        short8 v;
        #pragma unroll
        for (int j = 0; j < 8; j++) v[j] = (short)Ls[kl2 + j][nl2];
        *(short8*)(out + (size_t)(n0 + nl2) * K + k0 + kl2) = v;
    }
}

// ---------------------------------------------------------------------------
// m97-style GEMM: C[M x N] = A[M][1024]bf16 * Bt[N][1024]bf16^T + bias(fp32)
// 128x128 tile, BK=32, 4 waves x 64x64 quadrant, global_load_lds staging.
// MODE 0 (N=3072): scatter bf16 -> Q[Z,H,N,64] (PRE-SCALED by C_LOG2E, v11),
//   K[Z,H,N,64], V^T[Z,H,64,N].
//   v12: V-blocks (n0>=2048, pure-V since n-tiles are 128-aligned) use an
//   LDS-transpose epilogue: the old per-element V^T scatter hit stride-4096
//   (up to 64 cachelines per store instr, TA serialization, est ~30us of
//   GEMM0). Now: 2 passes (1 head each), acc -> LDS [64][130] transposed,
//   then coalesced 64B-run stores of V^T rows. Main loop untouched; LDS
//   still 32KB (buffer overlays As+Bs).
// MODE 1 (N=1024): fp32 store to outf.
// ---------------------------------------------------------------------------
template<int MODE>
__global__ __launch_bounds__(256)
void gemm_kernel(const unsigned short* __restrict__ A,
                 const unsigned short* __restrict__ Bt,
                 const float* __restrict__ bias,
                 unsigned short* __restrict__ out0,
                 unsigned short* __restrict__ out1,
                 unsigned short* __restrict__ out2,
                 float* __restrict__ outf)
{
    __shared__ __align__(16) unsigned short AsBs[2][128][32];
    unsigned short (&As)[128][32] = AsBs[0];
    unsigned short (&Bs)[128][32] = AsBs[1];
    const int t    = threadIdx.x;
    const int m0   = blockIdx.x * 128, n0 = blockIdx.y * 128;
    const int lane = t & 63, wv = t >> 6;
    const int l15  = lane & 15, quad = lane >> 4;
    const int wm   = (wv >> 1) * 64, wn = (wv & 1) * 64;
    const int sr   = wv * 16 + (lane >> 2);     // staging row (0..63)
    const int sc   = (lane & 3) * 8;            // staging col (k)
    const unsigned short* Ag = A  + (size_t)m0 * 1024;
    const unsigned short* Bg = Bt + (size_t)n0 * 1024;

    f32x4 acc[4][4] = {};

    for (int kt = 0; kt < 1024; kt += 32) {
        __syncthreads();                        // prior iter's LDS reads done
        async_cp16(Ag + (size_t)(sr)      * 1024 + kt + sc, &As[sr][sc]);
        async_cp16(Ag + (size_t)(sr + 64) * 1024 + kt + sc, &As[sr + 64][sc]);
        async_cp16(Bg + (size_t)(sr)      * 1024 + kt + sc, &Bs[sr][sc]);
        async_cp16(Bg + (size_t)(sr + 64) * 1024 + kt + sc, &Bs[sr + 64][sc]);
        __syncthreads();                        // drains vmcnt (loads landed)

        bf16x8 af[4], bfr[4];
        #pragma unroll
        for (int mi = 0; mi < 4; mi++) af[mi]  = *(const bf16x8*)&As[wm + mi*16 + l15][quad*8];
        #pragma unroll
        for (int ni = 0; ni < 4; ni++) bfr[ni] = *(const bf16x8*)&Bs[wn + ni*16 + l15][quad*8];
        #pragma unroll
        for (int mi = 0; mi < 4; mi++)
            #pragma unroll
            for (int ni = 0; ni < 4; ni++)
                acc[mi][ni] = __builtin_amdgcn_mfma_f32_16x16x32_bf16(af[mi], bfr[ni], acc[mi][ni], 0, 0, 0);
    }

    if (MODE == 0 && n0 >= 2048) {
        // ---- V-block: LDS-transpose epilogue, coalesced V^T stores ----
        unsigned short (*Tb)[130] = (unsigned short (*)[130])&AsBs[0][0][0];  // 64x130 u16 = 16.6KB <= 32KB
        const int hbase = (n0 - 2048) >> 6;           // head of half 0; half 1 is hbase+1
        const int bb = m0 >> 12, ns0 = m0 & 4095;
        const int dd = t >> 2, seg = (t & 3) * 32;    // read-back: row dd, 32-u16 segment
        #pragma unroll
        for (int p = 0; p < 2; p++) {
            __syncthreads();                          // LDS free (loop reads / prior pass done)
            if ((wv & 1) == p) {                      // waves owning cols [p*64, p*64+64)
                #pragma unroll
                for (int mi = 0; mi < 4; mi++) {
                    #pragma unroll
                    for (int ni = 0; ni < 4; ni++) {
                        const int colL = ni*16 + l15; // 0..63 within half
                        const float bval = bias[n0 + p*64 + colL];
                        #pragma unroll
                        for (int r = 0; r < 4; r++) {
                            const int row = wm + mi*16 + quad*4 + r;   // 0..127
                            Tb[colL][row] = f2bf(acc[mi][ni][r] + bval);
                        }
                    }
                }
            }
            __syncthreads();
            // V^T[bb][hbase+p][dd][ns0 + 0..127]: 64 rows x 128 u16, coalesced
            const size_t obase =
                ((size_t)((bb * NH + hbase + p) * HD + dd)) * NSEQ + ns0 + seg;
            #pragma unroll
            for (int j = 0; j < 4; j++)
                *(short8*)(out2 + obase + j*8) = *(const short8*)&Tb[dd][seg + j*8];
        }
        return;
    }

    #pragma unroll
    for (int mi = 0; mi < 4; mi++) {
        #pragma unroll
        for (int ni = 0; ni < 4; ni++) {
            const int col  = n0 + wn + ni*16 + l15;
            const float bval = bias[col];
            #pragma unroll
            for (int r = 0; r < 4; r++) {
                const int row = m0 + wm + mi*16 + quad*4 + r;
                const float val = acc[mi][ni][r] + bval;
                if (MODE == 0) {
                    // n0 < 2048 here: only Q (pre-scaled) and K
                    const int which = col >> 10;          // 0=q 1=k
                    const int rem   = col & 1023;
                    const int h = rem >> 6, dd = rem & 63;
                    const int bb = row >> 12, ns = row & 4095;
                    const size_t off = ((size_t)((bb * NH + h) * NSEQ + ns)) * HD + dd;
                    if (which == 0) out0[off] = f2bf(val * C_LOG2E);  // pre-scaled Q
                    else            out1[off] = f2bf(val);
                } else {
                    outf[(size_t)row * 1024 + col] = val;
                }
            }
        }
    }
}

// ---------------------------------------------------------------------------
// Flash attention: block=(z,h,128 q-rows), 4 waves x 32 rows.  (v11 EXACT)
// Q arrives pre-scaled by C_LOG2E; QK accumulators init to -M_LOG2 (MFMA C-in
// carries the constant) so p = exp2(accs) directly. l-sum via ones-MFMA;
// in-register P via kappa-permuted PV; double-buffered global_load_lds
// staging; one barrier/tile.
// ---------------------------------------------------------------------------
__global__ __launch_bounds__(256, 4)
void attn_kernel(const unsigned short* __restrict__ qb,
                 const unsigned short* __restrict__ kb,
                 const unsigned short* __restrict__ vb,
                 unsigned short* __restrict__ ob)
{
    __shared__ __align__(16) unsigned short Ks[2][64 * 64];
    __shared__ __align__(16) unsigned short Vt[2][64 * 64];

    const int t    = threadIdx.x;
    const int wv   = t >> 6, lane = t & 63, l15 = lane & 15, quad = lane >> 4;
    const int q0   = blockIdx.x * 128;
    const int h    = blockIdx.y, b = blockIdx.z;
    const size_t bh = (size_t)(b * NH + h) * NSEQ * HD;
    const unsigned short* Qp  = qb + bh;
    const unsigned short* Kp  = kb + bh;
    const unsigned short* Vtp = vb + bh;

    bf16x8 aq[2][2];
    #pragma unroll
    for (int mi = 0; mi < 2; mi++) {
        const unsigned short* qrow =
            Qp + (size_t)(q0 + wv*32 + mi*16 + l15) * HD + quad*8;
        aq[mi][0] = *(const bf16x8*)(qrow);
        aq[mi][1] = *(const bf16x8*)(qrow + 32);
    }

    const bf16x8 ones8 = pack_bf16x8(0x3F803F80u, 0x3F803F80u,
                                     0x3F803F80u, 0x3F803F80u);  // 8x bf16 1.0
    const f32x4 minit = {-M_LOG2, -M_LOG2, -M_LOG2, -M_LOG2};

    f32x4 acc_l[2] = {};           // l[q] per C-layout row (quad*4+r)
    f32x4 acc_o[2][4] = {};

    const int srow = lane >> 3;                        // 0..7
    const int sg8  = ((lane & 7) ^ srow) * 8;          // u16 src granule off
    const int rA   = wv * 16 + srow;                   // rows, call 0
    const int rB   = rA + 8;                           // rows, call 1
    unsigned short* ldsKA0 = &Ks[0][(wv*16 + 0) * 64];
    unsigned short* ldsKB0 = &Ks[0][(wv*16 + 8) * 64];
    unsigned short* ldsVA0 = &Vt[0][(wv*16 + 0) * 64];
    unsigned short* ldsVB0 = &Vt[0][(wv*16 + 8) * 64];
    unsigned short* ldsKA1 = &Ks[1][(wv*16 + 0) * 64];
    unsigned short* ldsKB1 = &Ks[1][(wv*16 + 8) * 64];
    unsigned short* ldsVA1 = &Vt[1][(wv*16 + 0) * 64];
    unsigned short* ldsVB1 = &Vt[1][(wv*16 + 8) * 64];

    // prologue: stage tile 0 into buffer 0
    async_cp16(Kp  + (size_t)rA * HD + sg8,   ldsKA0);
    async_cp16(Kp  + (size_t)rB * HD + sg8,   ldsKB0);
    async_cp16(Vtp + (size_t)rA * NSEQ + sg8, ldsVA0);
    async_cp16(Vtp + (size_t)rB * NSEQ + sg8, ldsVB0);

    int cur = 0;
    for (int kt = 0; kt < NSEQ; kt += 64) {
        __syncthreads();   // drains vmcnt (buf[cur] staged) + block barrier

        // issue next tile into buf[cur^1]; flies under this tile's compute.
        if (kt + 64 < NSEQ) {
            const int ktn = kt + 64;
            async_cp16(Kp  + (size_t)(ktn + rA) * HD + sg8, cur ? ldsKA0 : ldsKA1);
            async_cp16(Kp  + (size_t)(ktn + rB) * HD + sg8, cur ? ldsKB0 : ldsKB1);
            async_cp16(Vtp + (size_t)rA * NSEQ + ktn + sg8, cur ? ldsVA0 : ldsVA1);
            async_cp16(Vtp + (size_t)rB * NSEQ + ktn + sg8, cur ? ldsVB0 : ldsVB1);
        }

        const unsigned short* Kc = Ks[cur];
        const unsigned short* Vc = Vt[cur];

        // S^T = K Q^T (swapped operands): lane owns
        // S[q = l15][k = nj*16 + quad*4 + r]. Accumulators start at -M_LOG2:
        // final accs = c*s - M (Q pre-scaled by c in GEMM0).
        f32x4 accs[2][4];
        #pragma unroll
        for (int mi = 0; mi < 2; mi++)
            #pragma unroll
            for (int nj = 0; nj < 4; nj++)
                accs[mi][nj] = minit;
        __builtin_amdgcn_s_setprio(1);
        #pragma unroll
        for (int nj = 0; nj < 4; nj++) {
            bf16x8 bk0 = *(const bf16x8*)&Kc[SWZ(nj*16 + l15, quad*8)];
            bf16x8 bk1 = *(const bf16x8*)&Kc[SWZ(nj*16 + l15, 32 + quad*8)];
            #pragma unroll
            for (int mi = 0; mi < 2; mi++) {
                accs[mi][nj] = __builtin_amdgcn_mfma_f32_16x16x32_bf16(bk0, aq[mi][0], accs[mi][nj], 0, 0, 0);
                accs[mi][nj] = __builtin_amdgcn_mfma_f32_16x16x32_bf16(bk1, aq[mi][1], accs[mi][nj], 0, 0, 0);
            }
        }
        __builtin_amdgcn_s_setprio(0);

        // fixed-max softmax: p = 2^(accs) — no fma needed. P stays in regs.
        uint2 pw[2][4];
        #pragma unroll
        for (int mi = 0; mi < 2; mi++) {
            #pragma unroll
            for (int nj = 0; nj < 4; nj++) {
                const float p0 = FAST_EXP2(accs[mi][nj][0]);
                const float p1 = FAST_EXP2(accs[mi][nj][1]);
                const float p2 = FAST_EXP2(accs[mi][nj][2]);
                const float p3 = FAST_EXP2(accs[mi][nj][3]);
                pw[mi][nj].x = cvt_pk_bf16(p0, p1);
                pw[mi][nj].y = cvt_pk_bf16(p2, p3);
            }
        }

        // P A-fragments (kappa order), shared by l-MFMA and PV
        bf16x8 apf[2][2];
        #pragma unroll
        for (int mi = 0; mi < 2; mi++)
            #pragma unroll
            for (int W = 0; W < 2; W++)
                apf[mi][W] = pack_bf16x8(pw[mi][2*W].x,   pw[mi][2*W].y,
                                         pw[mi][2*W+1].x, pw[mi][2*W+1].y);

        __builtin_amdgcn_s_setprio(1);
        // l[q] += P . 1^T : lands in C layout row = quad*4+r (acc_o's rows).
        #pragma unroll
        for (int mi = 0; mi < 2; mi++) {
            acc_l[mi] = __builtin_amdgcn_mfma_f32_16x16x32_bf16(apf[mi][0], ones8, acc_l[mi], 0, 0, 0);
            acc_l[mi] = __builtin_amdgcn_mfma_f32_16x16x32_bf16(apf[mi][1], ones8, acc_l[mi], 0, 0, 0);
        }

        // O += P V with kappa-permuted fragments (k = 32W+16(j>>2)+4q+(j&3))
        #pragma unroll
        for (int njd = 0; njd < 4; njd++) {
            const int drow = njd * 16 + l15;
            #pragma unroll
            for (int W = 0; W < 2; W++) {
                const uint32x2 lo = *(const uint32x2*)&Vc[SWZ(drow, W*32 + quad*4)];
                const uint32x2 hi = *(const uint32x2*)&Vc[SWZ(drow, W*32 + 16 + quad*4)];
                const bf16x8 bv = pack_bf16x8(lo[0], lo[1], hi[0], hi[1]);
                #pragma unroll
                for (int mi = 0; mi < 2; mi++) {
                    acc_o[mi][njd] = __builtin_amdgcn_mfma_f32_16x16x32_bf16(apf[mi][W], bv, acc_o[mi][njd], 0, 0, 0);
                }
            }
        }
        __builtin_amdgcn_s_setprio(0);

        cur ^= 1;
    }

    // acc_l[mi][r] = l for row quad*4+r — no cross-lane redistribution needed.
    #pragma unroll
    for (int mi = 0; mi < 2; mi++) {
        #pragma unroll
        for (int r = 0; r < 4; r++) {
            const float inv = 1.0f / acc_l[mi][r];
            const int row = q0 + wv*32 + mi*16 + quad*4 + r;
            const size_t base = ((size_t)(b * NSEQ + row)) * DIM + h * HD;
            #pragma unroll
            for (int nj = 0; nj < 4; nj++)
                ob[base + nj*16 + l15] = f2bf(acc_o[mi][nj][r] * inv);
        }
    }
}

extern "C" void kernel_launch(void* const* d_in, const int* in_sizes, int n_in,
                              void* d_out, int out_size, void* d_ws, size_t ws_size,
                              hipStream_t stream)
{
    const float *x = nullptr, *w_qkv = nullptr, *b_qkv = nullptr,
                *w_o = nullptr, *b_o = nullptr;
    for (int i = 0; i < n_in; i++) {
        switch (in_sizes[i]) {
            case 8388608: x     = (const float*)d_in[i]; break;
            case 3145728: w_qkv = (const float*)d_in[i]; break;
            case 3072:    b_qkv = (const float*)d_in[i]; break;
            case 1048576: w_o   = (const float*)d_in[i]; break;
            case 1024:    b_o   = (const float*)d_in[i]; break;
        }
    }
    float* out = (float*)d_out;                     // [2,4096,1024] fp32

    const size_t WQB  = (size_t)3072 * 1024;        // elems
    const size_t WOB  = (size_t)1024 * 1024;
    const size_t SEGB = (size_t)NSEQ * DIM;         // 4,194,304 elems / batch

    char* p = (char*)d_ws;
    unsigned short* wqb = (unsigned short*)p;  p += WQB * 2;
    unsigned short* wob = (unsigned short*)p;  p += WOB * 2;

    transpose_conv_kernel<3072, 1024><<<dim3(16, 48), 256, 0, stream>>>(w_qkv, wqb);
    transpose_conv_kernel<1024, 1024><<<dim3(16, 16), 256, 0, stream>>>(w_o, wob);

    const size_t tier1_bytes = (WQB + WOB + 2*SEGB + 3*2*SEGB) * 2;  // 75.5 MB
    if (ws_size >= tier1_bytes) {
        unsigned short* xb = (unsigned short*)p;  p += 2 * SEGB * 2;
        unsigned short* qb = (unsigned short*)p;  p += 2 * SEGB * 2;
        unsigned short* kb = (unsigned short*)p;  p += 2 * SEGB * 2;
        unsigned short* vb = (unsigned short*)p;
        unsigned short* ao = xb;                  // xb dead after GEMM1
        conv_kernel<<<4096, 256, 0, stream>>>(x, xb);
        gemm_kernel<0><<<dim3(64, 24), 256, 0, stream>>>(xb, wqb, b_qkv, qb, kb, vb, nullptr);
        attn_kernel<<<dim3(32, NH, 2), 256, 0, stream>>>(qb, kb, vb, ao);
        gemm_kernel<1><<<dim3(64, 8), 256, 0, stream>>>(ao, wob, b_o, nullptr, nullptr, nullptr, out);
    } else {
        // per-batch: peak 41.9 MB
        unsigned short* xb = (unsigned short*)p;  p += SEGB * 2;
        unsigned short* qb = (unsigned short*)p;  p += SEGB * 2;
        unsigned short* kb = (unsigned short*)p;  p += SEGB * 2;
        unsigned short* vb = (unsigned short*)p;
        unsigned short* ao = xb;
        for (int b = 0; b < 2; b++) {
            conv_kernel<<<2048, 256, 0, stream>>>(x + b * SEGB, xb);
            gemm_kernel<0><<<dim3(32, 24), 256, 0, stream>>>(xb, wqb, b_qkv, qb, kb, vb, nullptr);
            attn_kernel<<<dim3(32, NH, 1), 256, 0, stream>>>(qb, kb, vb, ao);
            gemm_kernel<1><<<dim3(32, 8), 256, 0, stream>>>(ao, wob, b_o, nullptr, nullptr, nullptr, out + b * SEGB);
        }
    }
}

// Round 12
// 335.925 us; speedup vs baseline: 1.0754x; 1.0170x over previous
//
#include <hip/hip_runtime.h>

typedef __attribute__((ext_vector_type(8))) __bf16 bf16x8;
typedef __attribute__((ext_vector_type(8))) short short8;
typedef __attribute__((ext_vector_type(4))) float f32x4;
typedef __attribute__((ext_vector_type(2))) unsigned int uint32x2;

#define C_LOG2E 0.1803368801111183f    // 0.125 * log2(e)  (softmax scale, exp2 domain)
#define M_LOG2  11.541560327111707f    // 8 * log2(e)      (fixed-max shift)

__device__ __forceinline__ unsigned short f2bf(float f) {
    union { float f; unsigned int i; } c; c.f = f;
    unsigned int r = c.i + 0x7fffu + ((c.i >> 16) & 1u);  // round-nearest-even
    return (unsigned short)(r >> 16);
}

// pack two f32 -> two bf16 in one VALU op (no builtin on gfx950; m240/m214)
__device__ __forceinline__ unsigned int cvt_pk_bf16(float lo, float hi) {
    unsigned int r;
    asm("v_cvt_pk_bf16_f32 %0, %1, %2" : "=v"(r) : "v"(lo), "v"(hi));
    return r;
}

__device__ __forceinline__ bf16x8 pack_bf16x8(unsigned int a, unsigned int b,
                                              unsigned int c, unsigned int d) {
    union { unsigned int u[4]; bf16x8 v; } x;
    x.u[0] = a; x.u[1] = b; x.u[2] = c; x.u[3] = d;
    return x.v;
}

#if __has_builtin(__builtin_amdgcn_exp2f)
#define FAST_EXP2(x) __builtin_amdgcn_exp2f(x)     // single v_exp_f32
#else
#define FAST_EXP2(x) __expf((x) * 0.6931471805599453f)
#endif

// async global->LDS, 16B per lane; LDS dest must be base + lane*16 in wave order
__device__ __forceinline__ void async_cp16(const unsigned short* g, unsigned short* l) {
    __builtin_amdgcn_global_load_lds(
        (const __attribute__((address_space(1))) unsigned int*)g,
        (__attribute__((address_space(3))) unsigned int*)l, 16, 0, 0);
}

#define DIM 1024
#define NSEQ 4096
#define NH 16
#define HD 64

// T2 XOR swizzle for 64-u16 (128B) linear rows: XOR the 16B-slot index
// (u16 bits 3-5) with row&7. Attn evidence (v4/v5): conflicts 2.94e7->8.4e6.
// v13: also used by the GEMM fragment reads (the old [128][32] layout was an
// 8-way conflict: row stride 16 banks -> 16 l15-rows on 2 bank-groups).
#define SWZ(row, col) (((row) << 6) + ((col) ^ (((row) & 7) << 3)))

// ---------------------------------------------------------------------------
// fp32 -> bf16 copy-convert, 8 elems/thread
// ---------------------------------------------------------------------------
__global__ __launch_bounds__(256)
void conv_kernel(const float* __restrict__ in, unsigned short* __restrict__ out)
{
    const int i = blockIdx.x * 256 + threadIdx.x;
    const float4 a0 = ((const float4*)in)[i * 2];
    const float4 a1 = ((const float4*)in)[i * 2 + 1];
    short8 v;
    v[0] = (short)f2bf(a0.x); v[1] = (short)f2bf(a0.y);
    v[2] = (short)f2bf(a0.z); v[3] = (short)f2bf(a0.w);
    v[4] = (short)f2bf(a1.x); v[5] = (short)f2bf(a1.y);
    v[6] = (short)f2bf(a1.z); v[7] = (short)f2bf(a1.w);
    ((short8*)out)[i] = v;
}

// ---------------------------------------------------------------------------
// w [K][N] fp32 -> wT [N][K] bf16, 64x64 LDS tile transpose
// ---------------------------------------------------------------------------
template<int N, int K>
__global__ __launch_bounds__(256)
void transpose_conv_kernel(const float* __restrict__ in, unsigned short* __restrict__ out)
{
    __shared__ unsigned short Ls[64][65];
    const int t  = threadIdx.x;
    const int k0 = blockIdx.x * 64, n0 = blockIdx.y * 64;
    const int kl = t >> 2, nl = (t & 3) * 16;
    const float* src = in + (size_t)(k0 + kl) * N + n0 + nl;
    #pragma unroll
    for (int i = 0; i < 4; i++) {
        float4 a = *(const float4*)(src + i * 4);
        Ls[kl][nl + i*4 + 0] = f2bf(a.x); Ls[kl][nl + i*4 + 1] = f2bf(a.y);
        Ls[kl][nl + i*4 + 2] = f2bf(a.z); Ls[kl][nl + i*4 + 3] = f2bf(a.w);
    }
    __syncthreads();
    const int kl2 = (t & 7) * 8;
    #pragma unroll
    for (int i = 0; i < 2; i++) {
        const int nl2 = (t >> 3) + i * 32;
        short8 v;
        #pragma unroll
        for (int j = 0; j < 8; j++) v[j] = (short)Ls[kl2 + j][nl2];
        *(short8*)(out + (size_t)(n0 + nl2) * K + k0 + kl2) = v;
    }
}

// ---------------------------------------------------------------------------
// GEMM: C[M x N] = A[M][1024]bf16 * Bt[N][1024]bf16^T + bias(fp32)
// 128x128 tile, 4 waves x 64x64 quadrant, global_load_lds staging.
// v13: BK=64 (was 32) + SWZ'd LDS.
//   - Barrier-drains halve: 16 iters x 2 barriers (32 MFMA per drain).
//   - Fragment reads were 8-way bank conflicts on the [128][32] layout;
//     SWZ (pre-swizzled global source granule ^= row&7, swizzled ds_read
//     col) makes them 2-way = free. Same involution as attn (HW-proven).
//   - LDS 32 KB (2 x 128x64 u16); VGPR unchanged (K-halves sequential).
// MODE 0 (N=3072): Q pre-scaled by C_LOG2E (v11); K rows; V via LDS-
//   transpose epilogue with coalesced V^T stores (v12).
// MODE 1 (N=1024): fp32 store to outf.
// ---------------------------------------------------------------------------
template<int MODE>
__global__ __launch_bounds__(256)
void gemm_kernel(const unsigned short* __restrict__ A,
                 const unsigned short* __restrict__ Bt,
                 const float* __restrict__ bias,
                 unsigned short* __restrict__ out0,
                 unsigned short* __restrict__ out1,
                 unsigned short* __restrict__ out2,
                 float* __restrict__ outf)
{
    __shared__ __align__(16) unsigned short AsBs[2][128 * 64];
    unsigned short* As = AsBs[0];
    unsigned short* Bs = AsBs[1];
    const int t    = threadIdx.x;
    const int m0   = blockIdx.x * 128, n0 = blockIdx.y * 128;
    const int lane = t & 63, wv = t >> 6;
    const int l15  = lane & 15, quad = lane >> 4;
    const int wm   = (wv >> 1) * 64, wn = (wv & 1) * 64;

    // staging: call j covers rows [j*32, j*32+32); thread t -> row j*32+(t>>3),
    // granule t&7. Global col pre-swizzled (granule ^= row&7; (t>>3)&7 since
    // 32-aligned bases don't change row&7). LDS dest linear: t*16B per call.
    const int srow8 = t >> 3;                         // 0..31
    const int scol  = (((t & 7) ^ (srow8 & 7)) * 8);  // pre-swizzled src col
    const int sdst  = t * 8;                          // u16, linear in t
    const unsigned short* Ag = A  + (size_t)m0 * 1024;
    const unsigned short* Bg = Bt + (size_t)n0 * 1024;

    f32x4 acc[4][4] = {};

    for (int kt = 0; kt < 1024; kt += 64) {
        __syncthreads();                        // prior iter's LDS reads done
        #pragma unroll
        for (int j = 0; j < 4; j++) {
            async_cp16(Ag + (size_t)(j*32 + srow8) * 1024 + kt + scol, &As[j*2048 + sdst]);
            async_cp16(Bg + (size_t)(j*32 + srow8) * 1024 + kt + scol, &Bs[j*2048 + sdst]);
        }
        __syncthreads();                        // drains vmcnt (loads landed)

        #pragma unroll
        for (int h = 0; h < 2; h++) {           // two K-halves, regs reused
            bf16x8 af[4], bfr[4];
            #pragma unroll
            for (int mi = 0; mi < 4; mi++)
                af[mi]  = *(const bf16x8*)&As[SWZ(wm + mi*16 + l15, h*32 + quad*8)];
            #pragma unroll
            for (int ni = 0; ni < 4; ni++)
                bfr[ni] = *(const bf16x8*)&Bs[SWZ(wn + ni*16 + l15, h*32 + quad*8)];
            #pragma unroll
            for (int mi = 0; mi < 4; mi++)
                #pragma unroll
                for (int ni = 0; ni < 4; ni++)
                    acc[mi][ni] = __builtin_amdgcn_mfma_f32_16x16x32_bf16(af[mi], bfr[ni], acc[mi][ni], 0, 0, 0);
        }
    }

    if (MODE == 0 && n0 >= 2048) {
        // ---- V-block: LDS-transpose epilogue, coalesced V^T stores ----
        unsigned short (*Tb)[130] = (unsigned short (*)[130])&AsBs[0][0];  // 16.6KB <= 32KB
        const int hbase = (n0 - 2048) >> 6;           // head of half 0; half 1 is hbase+1
        const int bb = m0 >> 12, ns0 = m0 & 4095;
        const int dd = t >> 2, seg = (t & 3) * 32;    // read-back: row dd, 32-u16 segment
        #pragma unroll
        for (int p = 0; p < 2; p++) {
            __syncthreads();                          // LDS free (loop reads / prior pass done)
            if ((wv & 1) == p) {                      // waves owning cols [p*64, p*64+64)
                #pragma unroll
                for (int mi = 0; mi < 4; mi++) {
                    #pragma unroll
                    for (int ni = 0; ni < 4; ni++) {
                        const int colL = ni*16 + l15; // 0..63 within half
                        const float bval = bias[n0 + p*64 + colL];
                        #pragma unroll
                        for (int r = 0; r < 4; r++) {
                            const int row = wm + mi*16 + quad*4 + r;   // 0..127
                            Tb[colL][row] = f2bf(acc[mi][ni][r] + bval);
                        }
                    }
                }
            }
            __syncthreads();
            // V^T[bb][hbase+p][dd][ns0 + 0..127]: 64 rows x 128 u16, coalesced
            const size_t obase =
                ((size_t)((bb * NH + hbase + p) * HD + dd)) * NSEQ + ns0 + seg;
            #pragma unroll
            for (int j = 0; j < 4; j++)
                *(short8*)(out2 + obase + j*8) = *(const short8*)&Tb[dd][seg + j*8];
        }
        return;
    }

    #pragma unroll
    for (int mi = 0; mi < 4; mi++) {
        #pragma unroll
        for (int ni = 0; ni < 4; ni++) {
            const int col  = n0 + wn + ni*16 + l15;
            const float bval = bias[col];
            #pragma unroll
            for (int r = 0; r < 4; r++) {
                const int row = m0 + wm + mi*16 + quad*4 + r;
                const float val = acc[mi][ni][r] + bval;
                if (MODE == 0) {
                    // n0 < 2048 here: only Q (pre-scaled) and K
                    const int which = col >> 10;          // 0=q 1=k
                    const int rem   = col & 1023;
                    const int h = rem >> 6, dd = rem & 63;
                    const int bb = row >> 12, ns = row & 4095;
                    const size_t off = ((size_t)((bb * NH + h) * NSEQ + ns)) * HD + dd;
                    if (which == 0) out0[off] = f2bf(val * C_LOG2E);  // pre-scaled Q
                    else            out1[off] = f2bf(val);
                } else {
                    outf[(size_t)row * 1024 + col] = val;
                }
            }
        }
    }
}

// ---------------------------------------------------------------------------
// Flash attention: block=(z,h,128 q-rows), 4 waves x 32 rows.  (v11 EXACT)
// Q arrives pre-scaled by C_LOG2E; QK accumulators init to -M_LOG2 (MFMA C-in
// carries the constant) so p = exp2(accs) directly. l-sum via ones-MFMA;
// in-register P via kappa-permuted PV; double-buffered global_load_lds
// staging; one barrier/tile.
// ---------------------------------------------------------------------------
__global__ __launch_bounds__(256, 4)
void attn_kernel(const unsigned short* __restrict__ qb,
                 const unsigned short* __restrict__ kb,
                 const unsigned short* __restrict__ vb,
                 unsigned short* __restrict__ ob)
{
    __shared__ __align__(16) unsigned short Ks[2][64 * 64];
    __shared__ __align__(16) unsigned short Vt[2][64 * 64];

    const int t    = threadIdx.x;
    const int wv   = t >> 6, lane = t & 63, l15 = lane & 15, quad = lane >> 4;
    const int q0   = blockIdx.x * 128;
    const int h    = blockIdx.y, b = blockIdx.z;
    const size_t bh = (size_t)(b * NH + h) * NSEQ * HD;
    const unsigned short* Qp  = qb + bh;
    const unsigned short* Kp  = kb + bh;
    const unsigned short* Vtp = vb + bh;

    bf16x8 aq[2][2];
    #pragma unroll
    for (int mi = 0; mi < 2; mi++) {
        const unsigned short* qrow =
            Qp + (size_t)(q0 + wv*32 + mi*16 + l15) * HD + quad*8;
        aq[mi][0] = *(const bf16x8*)(qrow);
        aq[mi][1] = *(const bf16x8*)(qrow + 32);
    }

    const bf16x8 ones8 = pack_bf16x8(0x3F803F80u, 0x3F803F80u,
                                     0x3F803F80u, 0x3F803F80u);  // 8x bf16 1.0
    const f32x4 minit = {-M_LOG2, -M_LOG2, -M_LOG2, -M_LOG2};

    f32x4 acc_l[2] = {};           // l[q] per C-layout row (quad*4+r)
    f32x4 acc_o[2][4] = {};

    const int srow = lane >> 3;                        // 0..7
    const int sg8  = ((lane & 7) ^ srow) * 8;          // u16 src granule off
    const int rA   = wv * 16 + srow;                   // rows, call 0
    const int rB   = rA + 8;                           // rows, call 1
    unsigned short* ldsKA0 = &Ks[0][(wv*16 + 0) * 64];
    unsigned short* ldsKB0 = &Ks[0][(wv*16 + 8) * 64];
    unsigned short* ldsVA0 = &Vt[0][(wv*16 + 0) * 64];
    unsigned short* ldsVB0 = &Vt[0][(wv*16 + 8) * 64];
    unsigned short* ldsKA1 = &Ks[1][(wv*16 + 0) * 64];
    unsigned short* ldsKB1 = &Ks[1][(wv*16 + 8) * 64];
    unsigned short* ldsVA1 = &Vt[1][(wv*16 + 0) * 64];
    unsigned short* ldsVB1 = &Vt[1][(wv*16 + 8) * 64];

    // prologue: stage tile 0 into buffer 0
    async_cp16(Kp  + (size_t)rA * HD + sg8,   ldsKA0);
    async_cp16(Kp  + (size_t)rB * HD + sg8,   ldsKB0);
    async_cp16(Vtp + (size_t)rA * NSEQ + sg8, ldsVA0);
    async_cp16(Vtp + (size_t)rB * NSEQ + sg8, ldsVB0);

    int cur = 0;
    for (int kt = 0; kt < NSEQ; kt += 64) {
        __syncthreads();   // drains vmcnt (buf[cur] staged) + block barrier

        // issue next tile into buf[cur^1]; flies under this tile's compute.
        if (kt + 64 < NSEQ) {
            const int ktn = kt + 64;
            async_cp16(Kp  + (size_t)(ktn + rA) * HD + sg8, cur ? ldsKA0 : ldsKA1);
            async_cp16(Kp  + (size_t)(ktn + rB) * HD + sg8, cur ? ldsKB0 : ldsKB1);
            async_cp16(Vtp + (size_t)rA * NSEQ + ktn + sg8, cur ? ldsVA0 : ldsVA1);
            async_cp16(Vtp + (size_t)rB * NSEQ + ktn + sg8, cur ? ldsVB0 : ldsVB1);
        }

        const unsigned short* Kc = Ks[cur];
        const unsigned short* Vc = Vt[cur];

        // S^T = K Q^T (swapped operands): lane owns
        // S[q = l15][k = nj*16 + quad*4 + r]. Accumulators start at -M_LOG2:
        // final accs = c*s - M (Q pre-scaled by c in GEMM0).
        f32x4 accs[2][4];
        #pragma unroll
        for (int mi = 0; mi < 2; mi++)
            #pragma unroll
            for (int nj = 0; nj < 4; nj++)
                accs[mi][nj] = minit;
        __builtin_amdgcn_s_setprio(1);
        #pragma unroll
        for (int nj = 0; nj < 4; nj++) {
            bf16x8 bk0 = *(const bf16x8*)&Kc[SWZ(nj*16 + l15, quad*8)];
            bf16x8 bk1 = *(const bf16x8*)&Kc[SWZ(nj*16 + l15, 32 + quad*8)];
            #pragma unroll
            for (int mi = 0; mi < 2; mi++) {
                accs[mi][nj] = __builtin_amdgcn_mfma_f32_16x16x32_bf16(bk0, aq[mi][0], accs[mi][nj], 0, 0, 0);
                accs[mi][nj] = __builtin_amdgcn_mfma_f32_16x16x32_bf16(bk1, aq[mi][1], accs[mi][nj], 0, 0, 0);
            }
        }
        __builtin_amdgcn_s_setprio(0);

        // fixed-max softmax: p = 2^(accs) — no fma needed. P stays in regs.
        uint2 pw[2][4];
        #pragma unroll
        for (int mi = 0; mi < 2; mi++) {
            #pragma unroll
            for (int nj = 0; nj < 4; nj++) {
                const float p0 = FAST_EXP2(accs[mi][nj][0]);
                const float p1 = FAST_EXP2(accs[mi][nj][1]);
                const float p2 = FAST_EXP2(accs[mi][nj][2]);
                const float p3 = FAST_EXP2(accs[mi][nj][3]);
                pw[mi][nj].x = cvt_pk_bf16(p0, p1);
                pw[mi][nj].y = cvt_pk_bf16(p2, p3);
            }
        }

        // P A-fragments (kappa order), shared by l-MFMA and PV
        bf16x8 apf[2][2];
        #pragma unroll
        for (int mi = 0; mi < 2; mi++)
            #pragma unroll
            for (int W = 0; W < 2; W++)
                apf[mi][W] = pack_bf16x8(pw[mi][2*W].x,   pw[mi][2*W].y,
                                         pw[mi][2*W+1].x, pw[mi][2*W+1].y);

        __builtin_amdgcn_s_setprio(1);
        // l[q] += P . 1^T : lands in C layout row = quad*4+r (acc_o's rows).
        #pragma unroll
        for (int mi = 0; mi < 2; mi++) {
            acc_l[mi] = __builtin_amdgcn_mfma_f32_16x16x32_bf16(apf[mi][0], ones8, acc_l[mi], 0, 0, 0);
            acc_l[mi] = __builtin_amdgcn_mfma_f32_16x16x32_bf16(apf[mi][1], ones8, acc_l[mi], 0, 0, 0);
        }

        // O += P V with kappa-permuted fragments (k = 32W+16(j>>2)+4q+(j&3))
        #pragma unroll
        for (int njd = 0; njd < 4; njd++) {
            const int drow = njd * 16 + l15;
            #pragma unroll
            for (int W = 0; W < 2; W++) {
                const uint32x2 lo = *(const uint32x2*)&Vc[SWZ(drow, W*32 + quad*4)];
                const uint32x2 hi = *(const uint32x2*)&Vc[SWZ(drow, W*32 + 16 + quad*4)];
                const bf16x8 bv = pack_bf16x8(lo[0], lo[1], hi[0], hi[1]);
                #pragma unroll
                for (int mi = 0; mi < 2; mi++) {
                    acc_o[mi][njd] = __builtin_amdgcn_mfma_f32_16x16x32_bf16(apf[mi][W], bv, acc_o[mi][njd], 0, 0, 0);
                }
            }
        }
        __builtin_amdgcn_s_setprio(0);

        cur ^= 1;
    }

    // acc_l[mi][r] = l for row quad*4+r — no cross-lane redistribution needed.
    #pragma unroll
    for (int mi = 0; mi < 2; mi++) {
        #pragma unroll
        for (int r = 0; r < 4; r++) {
            const float inv = 1.0f / acc_l[mi][r];
            const int row = q0 + wv*32 + mi*16 + quad*4 + r;
            const size_t base = ((size_t)(b * NSEQ + row)) * DIM + h * HD;
            #pragma unroll
            for (int nj = 0; nj < 4; nj++)
                ob[base + nj*16 + l15] = f2bf(acc_o[mi][nj][r] * inv);
        }
    }
}

extern "C" void kernel_launch(void* const* d_in, const int* in_sizes, int n_in,
                              void* d_out, int out_size, void* d_ws, size_t ws_size,
                              hipStream_t stream)
{
    const float *x = nullptr, *w_qkv = nullptr, *b_qkv = nullptr,
                *w_o = nullptr, *b_o = nullptr;
    for (int i = 0; i < n_in; i++) {
        switch (in_sizes[i]) {
            case 8388608: x     = (const float*)d_in[i]; break;
            case 3145728: w_qkv = (const float*)d_in[i]; break;
            case 3072:    b_qkv = (const float*)d_in[i]; break;
            case 1048576: w_o   = (const float*)d_in[i]; break;
            case 1024:    b_o   = (const float*)d_in[i]; break;
        }
    }
    float* out = (float*)d_out;                     // [2,4096,1024] fp32

    const size_t WQB  = (size_t)3072 * 1024;        // elems
    const size_t WOB  = (size_t)1024 * 1024;
    const size_t SEGB = (size_t)NSEQ * DIM;         // 4,194,304 elems / batch

    char* p = (char*)d_ws;
    unsigned short* wqb = (unsigned short*)p;  p += WQB * 2;
    unsigned short* wob = (unsigned short*)p;  p += WOB * 2;

    transpose_conv_kernel<3072, 1024><<<dim3(16, 48), 256, 0, stream>>>(w_qkv, wqb);
    transpose_conv_kernel<1024, 1024><<<dim3(16, 16), 256, 0, stream>>>(w_o, wob);

    const size_t tier1_bytes = (WQB + WOB + 2*SEGB + 3*2*SEGB) * 2;  // 75.5 MB
    if (ws_size >= tier1_bytes) {
        unsigned short* xb = (unsigned short*)p;  p += 2 * SEGB * 2;
        unsigned short* qb = (unsigned short*)p;  p += 2 * SEGB * 2;
        unsigned short* kb = (unsigned short*)p;  p += 2 * SEGB * 2;
        unsigned short* vb = (unsigned short*)p;
        unsigned short* ao = xb;                  // xb dead after GEMM1
        conv_kernel<<<4096, 256, 0, stream>>>(x, xb);
        gemm_kernel<0><<<dim3(64, 24), 256, 0, stream>>>(xb, wqb, b_qkv, qb, kb, vb, nullptr);
        attn_kernel<<<dim3(32, NH, 2), 256, 0, stream>>>(qb, kb, vb, ao);
        gemm_kernel<1><<<dim3(64, 8), 256, 0, stream>>>(ao, wob, b_o, nullptr, nullptr, nullptr, out);
    } else {
        // per-batch: peak 41.9 MB
        unsigned short* xb = (unsigned short*)p;  p += SEGB * 2;
        unsigned short* qb = (unsigned short*)p;  p += SEGB * 2;
        unsigned short* kb = (unsigned short*)p;  p += SEGB * 2;
        unsigned short* vb = (unsigned short*)p;
        unsigned short* ao = xb;
        for (int b = 0; b < 2; b++) {
            conv_kernel<<<2048, 256, 0, stream>>>(x + b * SEGB, xb);
            gemm_kernel<0><<<dim3(32, 24), 256, 0, stream>>>(xb, wqb, b_qkv, qb, kb, vb, nullptr);
            attn_kernel<<<dim3(32, NH, 1), 256, 0, stream>>>(qb, kb, vb, ao);
            gemm_kernel<1><<<dim3(32, 8), 256, 0, stream>>>(ao, wob, b_o, nullptr, nullptr, nullptr, out + b * SEGB);
        }
    }
}